// Round 7
// baseline (251.720 us; speedup 1.0000x reference)
//
#include <hip/hip_runtime.h>
#include <math.h>

// (B,N,D,H) = (2,2048,1024,16), HD=64, ROT=32
#define NN 2048
#define DD 1024
#define HH 16
#define OUTSZ (2*NN*DD)

typedef unsigned short u16;
typedef unsigned int u32;
typedef __attribute__((ext_vector_type(8))) short short8;     // 8 bf16 (4 VGPRs)
typedef __attribute__((ext_vector_type(4))) float floatx4;
typedef __attribute__((ext_vector_type(16))) float floatx16;
typedef __attribute__((ext_vector_type(4))) u32 uint4v;
typedef __attribute__((ext_vector_type(4))) unsigned short us4;
typedef __attribute__((ext_vector_type(8))) unsigned short us8;

__device__ __forceinline__ u16 f2bf(float x) {
    union { float f; unsigned u; } v; v.f = x;
    unsigned r = v.u + 0x7FFFu + ((v.u >> 16) & 1u);   // RNE
    return (u16)(r >> 16);
}

__device__ __forceinline__ float fexp2(float x) {
#if __has_builtin(__builtin_amdgcn_exp2f)
    return __builtin_amdgcn_exp2f(x);
#else
    return __expf(x * 0.69314718056f);
#endif
}

__device__ __forceinline__ void gl_lds16(const u16* g, u16* l) {
    __builtin_amdgcn_global_load_lds(
        (const __attribute__((address_space(1))) unsigned int*)g,
        (__attribute__((address_space(3))) unsigned int*)l, 16, 0, 0);
}

// ---------------------------------------------------------------------------
// fp32 -> bf16 cast, WEIGHTS ONLY (X cast is fused into proj staging, R7).
// 24 MB traffic (~5 us) vs the old 7-tensor 96 MB pass (~18-20 us).
// ---------------------------------------------------------------------------
struct CastArgs { const float* s[4]; u16* d[4]; int n[4]; };

__global__ __launch_bounds__(256)
void cast_bf16(CastArgs a) {
    const int ten = blockIdx.y;
    const float4* s = (const float4*)a.s[ten];
    us8* d = (us8*)a.d[ten];
    const int n8 = a.n[ten] >> 3;
    for (int i = blockIdx.x * 256 + threadIdx.x; i < n8; i += gridDim.x * 256) {
        float4 f0 = s[2 * i];
        float4 f1 = s[2 * i + 1];
        us8 u = {f2bf(f0.x), f2bf(f0.y), f2bf(f0.z), f2bf(f0.w),
                 f2bf(f1.x), f2bf(f1.y), f2bf(f1.z), f2bf(f1.w)};
        d[i] = u;
    }
}

// ---------------------------------------------------------------------------
// bf16 MFMA projection GEMM (R3 schedule): tile 128 x TN, BK=64, 256 thr.
// XCD-chunked bijective block remap (T1): A/W fetched once per XCD.
// R7: AF32 path fuses the fp32->bf16 cast of X into A-staging:
//   loads issued BEFORE the first barrier (global-only, no LDS hazard ->
//   latency hides under the barrier join), f2bf (bit-identical RNE) +
//   ds_write_b128 into the SAME swizzled LDS layout between the barriers.
// Removes the standalone X cast pass (72 MB HBM) at the cost of reading
// X fp32 here (+24 MB, L2-amortized by the XCD remap).
// ---------------------------------------------------------------------------
struct ProjArgs {
    const float* Xf[3];              // fp32 X for modes 0-2 (q,k,v)
    const u16* X3;                   // bf16 X for mode 3 (ctxb)
    const u16* W[4];
    float* outf[4];  u16* outb[4];
    const float* rot;
};

template<int TN, bool AF32>
__global__ __launch_bounds__(256)
void mfma_proj(ProjArgs a, int mode_base)
{
    constexpr int TNW = TN / 2;      // wave cols
    constexpr int NJ  = TNW / 16;    // B-fragments per wave
    constexpr u32 GX  = DD / TN;     // col tiles (8 or 16)
    constexpr u32 GY  = (2 * NN) / 128;

    __shared__ __align__(16) u16 As[128 * 64];
    __shared__ __align__(16) u16 Bs[TN * 64];

    // ---- XCD-aware bijective remap (grid total is a multiple of 8)
    const u32 bid = blockIdx.x + GX * (blockIdx.y + GY * blockIdx.z);
    const u32 nwg = GX * GY * gridDim.z;
    const u32 wid = (bid & 7) * (nwg >> 3) + (bid >> 3);
    const u32 bx  = wid % GX;
    const u32 by  = (wid / GX) % GY;
    const u32 bz  = wid / (GX * GY);

    const int mode = mode_base + bz;
    const u16* __restrict__ Wm  = a.W[mode];
    float* __restrict__ outf    = a.outf[mode];
    u16* __restrict__ outb      = a.outb[mode];
    const float* __restrict__ rot = a.rot;

    const int t    = threadIdx.x;
    const int lane = t & 63;
    const int w    = t >> 6;
    const int wr   = (w >> 1) * 64;
    const int wc   = (w & 1) * TNW;
    const int m0   = by * 128;
    const int j0   = bx * TN;

    const int lc = (t & 7) ^ ((t >> 3) & 7);
    const float* gAf = AF32 ? (a.Xf[mode] + (size_t)(m0 + (t >> 3)) * DD + lc * 8) : nullptr;
    const u16*   gA  = AF32 ? nullptr : (a.X3 + (size_t)(m0 + (t >> 3)) * DD + lc * 8);
    const u16*   gB  = Wm + (size_t)(j0 + (t >> 3)) * DD + lc * 8;

    const int fr = lane & 15;
    const int fq = lane >> 4;

    floatx4 acc[4][NJ] = {};

    for (int k0 = 0; k0 < DD; k0 += 64) {
        float4 fA[4][2];
        if constexpr (AF32) {
            // issue A loads pre-barrier: global-only, previous compute reads LDS
            #pragma unroll
            for (int p = 0; p < 4; ++p) {
                const float* s = gAf + (size_t)(32 * p) * DD + k0;
                fA[p][0] = *(const float4*)(s);
                fA[p][1] = *(const float4*)(s + 4);
            }
        }
        __syncthreads();
        if constexpr (!AF32) {
            #pragma unroll
            for (int p = 0; p < 4; ++p)
                gl_lds16(gA + (size_t)(32 * p) * DD + k0, As + (p * 256 + t) * 8);
        } else {
            #pragma unroll
            for (int p = 0; p < 4; ++p) {
                us8 u = {f2bf(fA[p][0].x), f2bf(fA[p][0].y), f2bf(fA[p][0].z), f2bf(fA[p][0].w),
                         f2bf(fA[p][1].x), f2bf(fA[p][1].y), f2bf(fA[p][1].z), f2bf(fA[p][1].w)};
                *(us8*)(As + (p * 256 + t) * 8) = u;
            }
        }
        #pragma unroll
        for (int p = 0; p < TN / 32; ++p)
            gl_lds16(gB + (size_t)(32 * p) * DD + k0, Bs + (p * 256 + t) * 8);
        __syncthreads();
        #pragma unroll
        for (int kk = 0; kk < 2; ++kk) {
            const int ph = (kk * 4 + fq) ^ (fr & 7);
            short8 af[4], bf[NJ];
            #pragma unroll
            for (int i = 0; i < 4; ++i)
                af[i] = *(const short8*)(As + (wr + i * 16 + fr) * 64 + ph * 8);
            #pragma unroll
            for (int j = 0; j < NJ; ++j)
                bf[j] = *(const short8*)(Bs + (wc + j * 16 + fr) * 64 + ph * 8);
            #pragma unroll
            for (int i = 0; i < 4; ++i)
                #pragma unroll
                for (int j = 0; j < NJ; ++j)
                    acc[i][j] = __builtin_amdgcn_mfma_f32_16x16x32_bf16(af[i], bf[j], acc[i][j], 0, 0, 0);
        }
    }

    const int b = m0 >> 11;
    #pragma unroll
    for (int i = 0; i < 4; ++i) {
        const int mrow  = m0 + wr + i * 16 + fq * 4;   // + r
        const int nbase = mrow & (NN - 1);
        #pragma unroll
        for (int j = 0; j < NJ; ++j) {
            const int col = j0 + wc + j * 16 + fr;
            const int h = col >> 6, d = col & 63;
            const int bh = b * HH + h;
            float v[4];
            #pragma unroll
            for (int r = 0; r < 4; ++r) v[r] = acc[i][j][r];
            // rotary applies to head-dims d<32; d = ((wc+j*16)&63) + fr
            if (mode <= 1 && ((wc + j * 16) & 63) < 32) {
                #pragma unroll
                for (int r = 0; r < 4; ++r) {
                    const int n = nbase + r;
                    float c = v[r];
                    float p = __shfl_xor(c, 1);     // partner element d^1
                    float f = rot[n * 32 + d];
                    float sn, cs; __sincosf(f, &sn, &cs);
                    v[r] = (d & 1) ? fmaf(c, cs, p * sn) : fmaf(c, cs, -p * sn);
                }
            }
            if (mode == 0) {
                // fold softmax scale 1/8 and log2(e) into Q
                #pragma unroll
                for (int r = 0; r < 4; ++r)
                    outb[((size_t)bh * NN + nbase + r) * 64 + d] = f2bf(v[r] * 0.1803368801111244f);
            } else if (mode == 1) {
                float4 f4 = {v[0], v[1], v[2], v[3]};
                *(float4*)&outf[((size_t)bh * 64 + d) * NN + nbase] = f4;
                #pragma unroll
                for (int r = 0; r < 4; ++r)
                    outb[((size_t)bh * NN + nbase + r) * 64 + d] = f2bf(v[r]);
            } else if (mode == 2) {
                #pragma unroll
                for (int r = 0; r < 4; ++r)
                    outf[((size_t)bh * NN + nbase + r) * 64 + d] = v[r];
                us4 u = {f2bf(v[0]), f2bf(v[1]), f2bf(v[2]), f2bf(v[3])};
                *(us4*)&outb[((size_t)bh * 64 + d) * NN + nbase] = u;
            } else {
                #pragma unroll
                for (int r = 0; r < 4; ++r)
                    outf[(size_t)(mrow + r) * DD + col] = v[r];
            }
        }
    }
}

// ---------------------------------------------------------------------------
// bf16 MFMA flash attention v3: 32x32x16 MFMA, in-register P (T12).
// (unchanged from R6; setprio kept — null-to-noise here)
// ---------------------------------------------------------------------------
__global__ __launch_bounds__(256, 2)
void mfma_attn(const u16* __restrict__ qh, const u16* __restrict__ kh,
               const u16* __restrict__ vt, u16* __restrict__ ctx)
{
    __shared__ __align__(16) u16 Ks[2][128 * 64];   // [buf][key][hd], 16 KB each
    __shared__ __align__(16) u16 Vs[2][64 * 128];   // [buf][hd][key], 16 KB each

    const int t    = threadIdx.x;
    const int lane = t & 63;
    const int w    = t >> 6;
    const int m    = lane & 31;
    const int hi   = lane >> 5;
    const int bh   = blockIdx.x;                    // swizzle: bh on x (XCD-pinned head)
    const int q0   = blockIdx.y * 64;

    // Q fragments (B-operand): lane holds q = c*32+m, hd = kk*16+hi*8..+7
    short8 qf[2][4];
    #pragma unroll
    for (int c = 0; c < 2; ++c)
        #pragma unroll
        for (int kk = 0; kk < 4; ++kk)
            qf[c][kk] = *(const short8*)(qh +
                ((size_t)bh * NN + q0 + c * 32 + m) * 64 + kk * 16 + hi * 8);

    // staging sources (global-side pre-swizzle; linear LDS dest)
    const int kt = t >> 3, kc = t & 7;
    const u16* kg = kh + ((size_t)bh * NN + kt) * 64 + (kc ^ (kt & 7)) * 8;
    const int dt = t >> 4, vc = t & 15;
    const u16* vg = vt + ((size_t)bh * 64 + dt) * NN + (vc ^ (dt & 15)) * 8;

    // LDS fragment read offsets (u16 units), loop-invariant
    int kfo[4], vfo[2][2];
    #pragma unroll
    for (int kk = 0; kk < 4; ++kk)
        kfo[kk] = (w * 32 + m) * 64 + (((kk * 2 + hi) ^ (m & 7)) * 8);
    #pragma unroll
    for (int n = 0; n < 2; ++n)
        #pragma unroll
        for (int ks = 0; ks < 2; ++ks) {
            const int d = n * 32 + m;
            vfo[n][ks] = d * 128 + (((w * 4 + ks * 2 + hi) ^ (d & 15)) * 8);
        }

    floatx16 o[2][2] = {};                          // [q-tile c][d-tile n]
    float lrun[2] = {0.f, 0.f};

    // prologue: stage tile 0 into buf 0
    #pragma unroll
    for (int p = 0; p < 4; ++p) {
        gl_lds16(kg + (size_t)(p * 32) * 64, &Ks[0][(p * 256 + t) * 8]);
        gl_lds16(vg + (size_t)(p * 16) * NN, &Vs[0][(p * 256 + t) * 8]);
    }

    for (int it = 0; it < NN / 128; ++it) {
        const int cur = it & 1;
        __syncthreads();                            // drains stage loads + joins waves
        if (it + 1 < NN / 128) {
            const int j1 = (it + 1) * 128;
            #pragma unroll
            for (int p = 0; p < 4; ++p) {
                gl_lds16(kg + (size_t)(j1 + p * 32) * 64, &Ks[cur ^ 1][(p * 256 + t) * 8]);
                gl_lds16(vg + (size_t)(p * 16) * NN + j1, &Vs[cur ^ 1][(p * 256 + t) * 8]);
            }
        }
        const u16* kb = Ks[cur];
        const u16* vb = Vs[cur];

        short8 kf[4];
        #pragma unroll
        for (int kk = 0; kk < 4; ++kk)
            kf[kk] = *(const short8*)(kb + kfo[kk]);
        short8 vf[2][2];
        #pragma unroll
        for (int n = 0; n < 2; ++n)
            #pragma unroll
            for (int ks = 0; ks < 2; ++ks)
                vf[n][ks] = *(const short8*)(vb + vfo[n][ks]);

        // ---- S^T = K Q^T, two independent accumulator chains (q-tiles)
        floatx16 sT[2] = {};
        __builtin_amdgcn_s_setprio(1);
        #pragma unroll
        for (int kk = 0; kk < 4; ++kk) {
            sT[0] = __builtin_amdgcn_mfma_f32_32x32x16_bf16(kf[kk], qf[0][kk], sT[0], 0, 0, 0);
            sT[1] = __builtin_amdgcn_mfma_f32_32x32x16_bf16(kf[kk], qf[1][kk], sT[1], 0, 0, 0);
        }
        __builtin_amdgcn_s_setprio(0);

        // ---- per q-tile: exp2, l partial, pack to bf16, permlane-swap, PV
        #pragma unroll
        for (int c = 0; c < 2; ++c) {
            float p[16];
            #pragma unroll
            for (int r = 0; r < 16; ++r) p[r] = fexp2(sT[c][r]);
            lrun[c] += ((((p[0] + p[1]) + (p[2] + p[3])) + ((p[4] + p[5]) + (p[6] + p[7])))
                     + (((p[8] + p[9]) + (p[10] + p[11])) + ((p[12] + p[13]) + (p[14] + p[15]))));
            u32 W[8];
            #pragma unroll
            for (int s = 0; s < 8; ++s)
                asm("v_cvt_pk_bf16_f32 %0, %1, %2" : "=v"(W[s]) : "v"(p[2 * s]), "v"(p[2 * s + 1]));
            asm("v_permlane32_swap_b32 %0, %1" : "+v"(W[0]), "+v"(W[2]));
            asm("v_permlane32_swap_b32 %0, %1" : "+v"(W[1]), "+v"(W[3]));
            asm("v_permlane32_swap_b32 %0, %1" : "+v"(W[4]), "+v"(W[6]));
            asm("v_permlane32_swap_b32 %0, %1" : "+v"(W[5]), "+v"(W[7]));
            uint4v w0 = {W[0], W[1], W[2], W[3]};
            uint4v w1 = {W[4], W[5], W[6], W[7]};
            const short8 pa0 = __builtin_bit_cast(short8, w0);
            const short8 pa1 = __builtin_bit_cast(short8, w1);
            __builtin_amdgcn_s_setprio(1);
            #pragma unroll
            for (int n = 0; n < 2; ++n) {
                o[c][n] = __builtin_amdgcn_mfma_f32_32x32x16_bf16(pa0, vf[n][0], o[c][n], 0, 0, 0);
                o[c][n] = __builtin_amdgcn_mfma_f32_32x32x16_bf16(pa1, vf[n][1], o[c][n], 0, 0, 0);
            }
            __builtin_amdgcn_s_setprio(0);
        }
    }

    // ---- l: partner half holds the other 16 keys of the wave's 32
    #pragma unroll
    for (int c = 0; c < 2; ++c)
        lrun[c] += __shfl_xor(lrun[c], 32);

    // ---- cross-wave pair reduction in dead staging buffers:
    // waves 0,1 -> Osc0 (=Ks[0]); waves 2,3 -> Osc1 (=Ks[1]); merge at store.
    float* Osc0 = (float*)&Ks[0][0];                // [64 q][64 d]
    float* Osc1 = (float*)&Ks[1][0];
    float* Lv0  = (float*)&Vs[0][0];                // 64 floats
    float* Lv1  = Lv0 + 64;

    __syncthreads();                                // all tile reads done
    if ((w & 1) == 0) {                             // waves 0 and 2 in parallel
        float* O = (w == 0) ? Osc0 : Osc1;
        float* L = (w == 0) ? Lv0  : Lv1;
        #pragma unroll
        for (int c = 0; c < 2; ++c)
            #pragma unroll
            for (int n = 0; n < 2; ++n)
                #pragma unroll
                for (int r = 0; r < 16; ++r) {
                    const int q = c * 32 + (r & 3) + 8 * (r >> 2) + 4 * hi;
                    O[q * 64 + n * 32 + m] = o[c][n][r];
                }
        if (hi == 0) { L[m] = lrun[0]; L[32 + m] = lrun[1]; }
    }
    __syncthreads();
    if (w & 1) {                                    // waves 1 and 3 in parallel
        float* O = (w == 1) ? Osc0 : Osc1;
        float* L = (w == 1) ? Lv0  : Lv1;
        #pragma unroll
        for (int c = 0; c < 2; ++c)
            #pragma unroll
            for (int n = 0; n < 2; ++n)
                #pragma unroll
                for (int r = 0; r < 16; ++r) {
                    const int q = c * 32 + (r & 3) + 8 * (r >> 2) + 4 * hi;
                    O[q * 64 + n * 32 + m] += o[c][n][r];
                }
        if (hi == 0) { L[m] += lrun[0]; L[32 + m] += lrun[1]; }
    }
    __syncthreads();

    // ---- merge halves, normalize, write ctx (B,N,D) bf16
    const int b = bh >> 4, h = bh & 15;
    const int q = t >> 2;                           // 0..63
    const float inv = 1.0f / (Lv0[q] + Lv1[q]);
    #pragma unroll
    for (int i = 0; i < 4; ++i) {
        const int d0 = (t & 3) * 16 + i * 4;
        const float4 oa = *(const float4*)(Osc0 + q * 64 + d0);
        const float4 ob = *(const float4*)(Osc1 + q * 64 + d0);
        us4 u = {f2bf((oa.x + ob.x) * inv), f2bf((oa.y + ob.y) * inv),
                 f2bf((oa.z + ob.z) * inv), f2bf((oa.w + ob.w) * inv)};
        *(us4*)&ctx[((size_t)b * NN + q0 + q) * DD + h * 64 + d0] = u;
    }
}

// ---------------------------------------------------------------------------
extern "C" void kernel_launch(void* const* d_in, const int* in_sizes, int n_in,
                              void* d_out, int out_size, void* d_ws, size_t ws_size,
                              hipStream_t stream)
{
    const float* q   = (const float*)d_in[0];
    const float* k   = (const float*)d_in[1];
    const float* v   = (const float*)d_in[2];
    const float* wq  = (const float*)d_in[3];
    const float* wk  = (const float*)d_in[4];
    const float* wv  = (const float*)d_in[5];
    const float* wo  = (const float*)d_in[6];
    const float* rot = (const float*)d_in[7];

    float* out_final = (float*)d_out;            // (B,N,D)
    float* out_kt    = out_final + OUTSZ;        // (B,H,HD,N)
    float* out_vh    = out_kt + OUTSZ;           // (B,H,N,HD)

    u16* wsb  = (u16*)d_ws;
    u16* wqb  = wsb + (size_t)12 * 1024 * 1024;
    u16* wkb  = wsb + (size_t)13 * 1024 * 1024;
    u16* wvb  = wsb + (size_t)14 * 1024 * 1024;
    u16* wob  = wsb + (size_t)15 * 1024 * 1024;
    u16* qhb  = wsb + (size_t)16 * 1024 * 1024;  // (B,H,N,HD), pre-scaled 0.125*log2e
    u16* khb  = wsb + (size_t)20 * 1024 * 1024;  // (B,H,N,HD)
    u16* vtb  = wsb + (size_t)24 * 1024 * 1024;  // (B,H,HD,N)
    u16* ctxb = wsb + (size_t)28 * 1024 * 1024;  // (B,N,D)

    CastArgs ca;
    ca.s[0] = wq; ca.d[0] = wqb; ca.n[0] = DD * DD;
    ca.s[1] = wk; ca.d[1] = wkb; ca.n[1] = DD * DD;
    ca.s[2] = wv; ca.d[2] = wvb; ca.n[2] = DD * DD;
    ca.s[3] = wo; ca.d[3] = wob; ca.n[3] = DD * DD;
    cast_bf16<<<dim3(128, 4), 256, 0, stream>>>(ca);

    ProjArgs pa;
    pa.Xf[0] = q; pa.Xf[1] = k; pa.Xf[2] = v;
    pa.X3 = ctxb;
    pa.W[0] = wqb; pa.outf[0] = nullptr;   pa.outb[0] = qhb;
    pa.W[1] = wkb; pa.outf[1] = out_kt;    pa.outb[1] = khb;
    pa.W[2] = wvb; pa.outf[2] = out_vh;    pa.outb[2] = vtb;
    pa.W[3] = wob; pa.outf[3] = out_final; pa.outb[3] = nullptr;
    pa.rot = rot;

    // fused Q/K/V projections: 768 blocks, 128x128 tiles, BK=64, fused X cast
    mfma_proj<128, true><<<dim3(DD / 128, (2 * NN) / 128, 3), 256, 0, stream>>>(pa, 0);

    // attention: grid (bh, qtile) so one head pins to one XCD
    mfma_attn<<<dim3(2 * HH, NN / 64), 256, 0, stream>>>(qhb, khb, vtb, ctxb);

    // final projection: 512 blocks (2/CU), 128x64 tiles, BK=64, bf16 X (ctxb)
    mfma_proj<64, false><<<dim3(DD / 64, (2 * NN) / 128, 1), 256, 0, stream>>>(pa, 3);
}

// Round 8
// 237.027 us; speedup vs baseline: 1.0620x; 1.0620x over previous
//
#include <hip/hip_runtime.h>
#include <math.h>

// (B,N,D,H) = (2,2048,1024,16), HD=64, ROT=32
#define NN 2048
#define DD 1024
#define HH 16
#define OUTSZ (2*NN*DD)

typedef unsigned short u16;
typedef unsigned int u32;
typedef __attribute__((ext_vector_type(8))) short short8;     // 8 bf16 (4 VGPRs)
typedef __attribute__((ext_vector_type(4))) float floatx4;
typedef __attribute__((ext_vector_type(16))) float floatx16;
typedef __attribute__((ext_vector_type(4))) u32 uint4v;
typedef __attribute__((ext_vector_type(4))) unsigned short us4;
typedef __attribute__((ext_vector_type(8))) unsigned short us8;

__device__ __forceinline__ u16 f2bf(float x) {
    union { float f; unsigned u; } v; v.f = x;
    unsigned r = v.u + 0x7FFFu + ((v.u >> 16) & 1u);   // RNE
    return (u16)(r >> 16);
}

__device__ __forceinline__ float fexp2(float x) {
#if __has_builtin(__builtin_amdgcn_exp2f)
    return __builtin_amdgcn_exp2f(x);
#else
    return __expf(x * 0.69314718056f);
#endif
}

__device__ __forceinline__ void gl_lds16(const u16* g, u16* l) {
    __builtin_amdgcn_global_load_lds(
        (const __attribute__((address_space(1))) unsigned int*)g,
        (__attribute__((address_space(3))) unsigned int*)l, 16, 0, 0);
}

// ---------------------------------------------------------------------------
// fp32 -> bf16 cast for q,k,v + 4 weights (R6 version — standalone cast is
// faster than fusing into proj staging: R7 showed reg-staged loads are fully
// latency-exposed inside a __syncthreads loop).
// ---------------------------------------------------------------------------
struct CastArgs { const float* s[7]; u16* d[7]; int n[7]; };

__global__ __launch_bounds__(256)
void cast_bf16(CastArgs a) {
    const int ten = blockIdx.y;
    const float4* s = (const float4*)a.s[ten];
    us8* d = (us8*)a.d[ten];
    const int n8 = a.n[ten] >> 3;
    for (int i = blockIdx.x * 256 + threadIdx.x; i < n8; i += gridDim.x * 256) {
        float4 f0 = s[2 * i];
        float4 f1 = s[2 * i + 1];
        us8 u = {f2bf(f0.x), f2bf(f0.y), f2bf(f0.z), f2bf(f0.w),
                 f2bf(f1.x), f2bf(f1.y), f2bf(f1.z), f2bf(f1.w)};
        d[i] = u;
    }
}

// ---------------------------------------------------------------------------
// bf16 MFMA projection GEMM (exact R3/R6): tile 128 x TN, BK=64, 256 thr.
// XCD-chunked bijective block remap (T1): FETCH at ideal 30 MB, 0 conflicts.
// ---------------------------------------------------------------------------
struct ProjArgs {
    const u16* X[4]; const u16* W[4];
    float* outf[4];  u16* outb[4];
    const float* rot;
};

template<int TN>
__global__ __launch_bounds__(256)
void mfma_proj(ProjArgs a, int mode_base)
{
    constexpr int TNW = TN / 2;      // wave cols
    constexpr int NJ  = TNW / 16;    // B-fragments per wave
    constexpr u32 GX  = DD / TN;     // col tiles (8 or 16)
    constexpr u32 GY  = (2 * NN) / 128;

    __shared__ __align__(16) u16 As[128 * 64];
    __shared__ __align__(16) u16 Bs[TN * 64];

    // ---- XCD-aware bijective remap (grid total is a multiple of 8)
    const u32 bid = blockIdx.x + GX * (blockIdx.y + GY * blockIdx.z);
    const u32 nwg = GX * GY * gridDim.z;
    const u32 wid = (bid & 7) * (nwg >> 3) + (bid >> 3);
    const u32 bx  = wid % GX;
    const u32 by  = (wid / GX) % GY;
    const u32 bz  = wid / (GX * GY);

    const int mode = mode_base + bz;
    const u16* __restrict__ X   = a.X[mode];
    const u16* __restrict__ Wm  = a.W[mode];
    float* __restrict__ outf    = a.outf[mode];
    u16* __restrict__ outb      = a.outb[mode];
    const float* __restrict__ rot = a.rot;

    const int t    = threadIdx.x;
    const int lane = t & 63;
    const int w    = t >> 6;
    const int wr   = (w >> 1) * 64;
    const int wc   = (w & 1) * TNW;
    const int m0   = by * 128;
    const int j0   = bx * TN;

    const int lc = (t & 7) ^ ((t >> 3) & 7);
    const u16* gA = X  + (size_t)(m0 + (t >> 3)) * DD + lc * 8;
    const u16* gB = Wm + (size_t)(j0 + (t >> 3)) * DD + lc * 8;

    const int fr = lane & 15;
    const int fq = lane >> 4;

    floatx4 acc[4][NJ] = {};

    for (int k0 = 0; k0 < DD; k0 += 64) {
        __syncthreads();
        #pragma unroll
        for (int p = 0; p < 4; ++p)
            gl_lds16(gA + (size_t)(32 * p) * DD + k0, As + (p * 256 + t) * 8);
        #pragma unroll
        for (int p = 0; p < TN / 32; ++p)
            gl_lds16(gB + (size_t)(32 * p) * DD + k0, Bs + (p * 256 + t) * 8);
        __syncthreads();
        #pragma unroll
        for (int kk = 0; kk < 2; ++kk) {
            const int ph = (kk * 4 + fq) ^ (fr & 7);
            short8 af[4], bf[NJ];
            #pragma unroll
            for (int i = 0; i < 4; ++i)
                af[i] = *(const short8*)(As + (wr + i * 16 + fr) * 64 + ph * 8);
            #pragma unroll
            for (int j = 0; j < NJ; ++j)
                bf[j] = *(const short8*)(Bs + (wc + j * 16 + fr) * 64 + ph * 8);
            #pragma unroll
            for (int i = 0; i < 4; ++i)
                #pragma unroll
                for (int j = 0; j < NJ; ++j)
                    acc[i][j] = __builtin_amdgcn_mfma_f32_16x16x32_bf16(af[i], bf[j], acc[i][j], 0, 0, 0);
        }
    }

    const int b = m0 >> 11;
    #pragma unroll
    for (int i = 0; i < 4; ++i) {
        const int mrow  = m0 + wr + i * 16 + fq * 4;   // + r
        const int nbase = mrow & (NN - 1);
        #pragma unroll
        for (int j = 0; j < NJ; ++j) {
            const int col = j0 + wc + j * 16 + fr;
            const int h = col >> 6, d = col & 63;
            const int bh = b * HH + h;
            float v[4];
            #pragma unroll
            for (int r = 0; r < 4; ++r) v[r] = acc[i][j][r];
            // rotary applies to head-dims d<32; d = ((wc+j*16)&63) + fr
            if (mode <= 1 && ((wc + j * 16) & 63) < 32) {
                #pragma unroll
                for (int r = 0; r < 4; ++r) {
                    const int n = nbase + r;
                    float c = v[r];
                    float p = __shfl_xor(c, 1);     // partner element d^1
                    float f = rot[n * 32 + d];
                    float sn, cs; __sincosf(f, &sn, &cs);
                    v[r] = (d & 1) ? fmaf(c, cs, p * sn) : fmaf(c, cs, -p * sn);
                }
            }
            if (mode == 0) {
                // fold softmax scale 1/8 and log2(e) into Q
                #pragma unroll
                for (int r = 0; r < 4; ++r)
                    outb[((size_t)bh * NN + nbase + r) * 64 + d] = f2bf(v[r] * 0.1803368801111244f);
            } else if (mode == 1) {
                float4 f4 = {v[0], v[1], v[2], v[3]};
                *(float4*)&outf[((size_t)bh * 64 + d) * NN + nbase] = f4;
                #pragma unroll
                for (int r = 0; r < 4; ++r)
                    outb[((size_t)bh * NN + nbase + r) * 64 + d] = f2bf(v[r]);
            } else if (mode == 2) {
                #pragma unroll
                for (int r = 0; r < 4; ++r)
                    outf[((size_t)bh * NN + nbase + r) * 64 + d] = v[r];
                us4 u = {f2bf(v[0]), f2bf(v[1]), f2bf(v[2]), f2bf(v[3])};
                *(us4*)&outb[((size_t)bh * 64 + d) * NN + nbase] = u;
            } else {
                #pragma unroll
                for (int r = 0; r < 4; ++r)
                    outf[(size_t)(mrow + r) * DD + col] = v[r];
            }
        }
    }
}

// ---------------------------------------------------------------------------
// bf16 MFMA flash attention v4: QBLK=128, 512 thr, 8 waves = 2 q-halves (g)
// x 4 key-slices (s). Per-wave pipeline identical to the verified v3
// (32x32 swapped QK^T, in-register P via cvt_pk + permlane32_swap).
// K/V staged ONCE per 128 queries (was per 64) -> staging traffic and
// issue count per query halve (4 gl_lds/thread/iter, was 8).
// Epilogue: 4 key-slice rounds, both q-halves in parallel; Osc in dead Ks.
// ---------------------------------------------------------------------------
__global__ __launch_bounds__(512, 2)
void mfma_attn(const u16* __restrict__ qh, const u16* __restrict__ kh,
               const u16* __restrict__ vt, u16* __restrict__ ctx)
{
    __shared__ __align__(16) u16 Ks[2][128 * 64];   // [buf][key][hd], 16 KB each
    __shared__ __align__(16) u16 Vs[2][64 * 128];   // [buf][hd][key], 16 KB each

    const int t    = threadIdx.x;
    const int lane = t & 63;
    const int w    = t >> 6;                        // 0..7
    const int m    = lane & 31;
    const int hi   = lane >> 5;
    const int g    = w >> 2;                        // q-half
    const int s    = w & 3;                         // key-slice
    const int bh   = blockIdx.x;                    // head -> XCD pin (bh%8)
    const int q0   = blockIdx.y * 128;

    // Q fragments (B-operand): lane holds q = q0+g*64+c*32+m, hd = kk*16+hi*8..
    short8 qf[2][4];
    #pragma unroll
    for (int c = 0; c < 2; ++c)
        #pragma unroll
        for (int kk = 0; kk < 4; ++kk)
            qf[c][kk] = *(const short8*)(qh +
                ((size_t)bh * NN + q0 + g * 64 + c * 32 + m) * 64 + kk * 16 + hi * 8);

    // staging (512 thr): K row kr(+64), V row dt(+32); global-side pre-swizzle
    const int kr = t >> 3, kc = t & 7;
    const u16* kg = kh + ((size_t)bh * NN + kr) * 64 + (kc ^ (kr & 7)) * 8;
    const int dt = t >> 4, vc = t & 15;
    const u16* vg = vt + ((size_t)bh * 64 + dt) * NN + (vc ^ (dt & 15)) * 8;

    // LDS fragment read offsets (u16 units), loop-invariant
    int kfo[4], vfo[2][2];
    #pragma unroll
    for (int kk = 0; kk < 4; ++kk)
        kfo[kk] = (s * 32 + m) * 64 + (((kk * 2 + hi) ^ (m & 7)) * 8);
    #pragma unroll
    for (int n = 0; n < 2; ++n)
        #pragma unroll
        for (int ks = 0; ks < 2; ++ks) {
            const int d = n * 32 + m;
            vfo[n][ks] = d * 128 + (((s * 4 + ks * 2 + hi) ^ (d & 15)) * 8);
        }

    floatx16 o[2][2] = {};                          // [q-tile c][d-tile n]
    float lrun[2] = {0.f, 0.f};

    // prologue: stage tile 0 into buf 0 (2 K + 2 V loads per thread)
    #pragma unroll
    for (int p = 0; p < 2; ++p) {
        gl_lds16(kg + (size_t)(p * 64) * 64, &Ks[0][(p * 512 + t) * 8]);
        gl_lds16(vg + (size_t)(p * 32) * NN, &Vs[0][(p * 512 + t) * 8]);
    }

    for (int it = 0; it < NN / 128; ++it) {
        const int cur = it & 1;
        __syncthreads();                            // drains stage loads + joins waves
        if (it + 1 < NN / 128) {
            const int j1 = (it + 1) * 128;
            #pragma unroll
            for (int p = 0; p < 2; ++p) {
                gl_lds16(kg + (size_t)(j1 + p * 64) * 64, &Ks[cur ^ 1][(p * 512 + t) * 8]);
                gl_lds16(vg + (size_t)(p * 32) * NN + j1, &Vs[cur ^ 1][(p * 512 + t) * 8]);
            }
        }
        const u16* kb = Ks[cur];
        const u16* vb = Vs[cur];

        short8 kf[4];
        #pragma unroll
        for (int kk = 0; kk < 4; ++kk)
            kf[kk] = *(const short8*)(kb + kfo[kk]);
        short8 vf[2][2];
        #pragma unroll
        for (int n = 0; n < 2; ++n)
            #pragma unroll
            for (int ks = 0; ks < 2; ++ks)
                vf[n][ks] = *(const short8*)(vb + vfo[n][ks]);

        // ---- S^T = K Q^T, two independent accumulator chains (q-tiles)
        floatx16 sT[2] = {};
        __builtin_amdgcn_s_setprio(1);
        #pragma unroll
        for (int kk = 0; kk < 4; ++kk) {
            sT[0] = __builtin_amdgcn_mfma_f32_32x32x16_bf16(kf[kk], qf[0][kk], sT[0], 0, 0, 0);
            sT[1] = __builtin_amdgcn_mfma_f32_32x32x16_bf16(kf[kk], qf[1][kk], sT[1], 0, 0, 0);
        }
        __builtin_amdgcn_s_setprio(0);

        // ---- per q-tile: exp2, l partial, pack to bf16, permlane-swap, PV
        #pragma unroll
        for (int c = 0; c < 2; ++c) {
            float p[16];
            #pragma unroll
            for (int r = 0; r < 16; ++r) p[r] = fexp2(sT[c][r]);
            lrun[c] += ((((p[0] + p[1]) + (p[2] + p[3])) + ((p[4] + p[5]) + (p[6] + p[7])))
                     + (((p[8] + p[9]) + (p[10] + p[11])) + ((p[12] + p[13]) + (p[14] + p[15]))));
            u32 W[8];
            #pragma unroll
            for (int ss = 0; ss < 8; ++ss)
                asm("v_cvt_pk_bf16_f32 %0, %1, %2" : "=v"(W[ss]) : "v"(p[2 * ss]), "v"(p[2 * ss + 1]));
            asm("v_permlane32_swap_b32 %0, %1" : "+v"(W[0]), "+v"(W[2]));
            asm("v_permlane32_swap_b32 %0, %1" : "+v"(W[1]), "+v"(W[3]));
            asm("v_permlane32_swap_b32 %0, %1" : "+v"(W[4]), "+v"(W[6]));
            asm("v_permlane32_swap_b32 %0, %1" : "+v"(W[5]), "+v"(W[7]));
            uint4v w0 = {W[0], W[1], W[2], W[3]};
            uint4v w1 = {W[4], W[5], W[6], W[7]};
            const short8 pa0 = __builtin_bit_cast(short8, w0);
            const short8 pa1 = __builtin_bit_cast(short8, w1);
            __builtin_amdgcn_s_setprio(1);
            #pragma unroll
            for (int n = 0; n < 2; ++n) {
                o[c][n] = __builtin_amdgcn_mfma_f32_32x32x16_bf16(pa0, vf[n][0], o[c][n], 0, 0, 0);
                o[c][n] = __builtin_amdgcn_mfma_f32_32x32x16_bf16(pa1, vf[n][1], o[c][n], 0, 0, 0);
            }
            __builtin_amdgcn_s_setprio(0);
        }
    }

    // ---- l: partner half holds the other 16 keys of the wave's 32
    #pragma unroll
    for (int c = 0; c < 2; ++c)
        lrun[c] += __shfl_xor(lrun[c], 32);

    // ---- cross-wave reduction over 4 key-slices (both q-halves parallel).
    // Dead staging buffers: Osc = Ks (32 KB = [2 g][64 q][64 d] fp32),
    // Lv = Vs ([2 g][64 q] fp32).
    float* Osc = (float*)&Ks[0][0];
    float* Lv  = (float*)&Vs[0][0];

    __syncthreads();                                // all tile reads done
    #pragma unroll
    for (int rnd = 0; rnd < 4; ++rnd) {
        if (s == rnd) {
            float* O = Osc + g * 4096;
            #pragma unroll
            for (int c = 0; c < 2; ++c) {
                #pragma unroll
                for (int n = 0; n < 2; ++n)
                    #pragma unroll
                    for (int r = 0; r < 16; ++r) {
                        const int q = c * 32 + (r & 3) + 8 * (r >> 2) + 4 * hi;
                        if (rnd == 0) O[q * 64 + n * 32 + m] = o[c][n][r];
                        else          O[q * 64 + n * 32 + m] += o[c][n][r];
                    }
                if (hi == 0) {
                    const int ql = g * 64 + c * 32 + m;
                    if (rnd == 0) Lv[ql] = lrun[c];
                    else          Lv[ql] += lrun[c];
                }
            }
        }
        __syncthreads();
    }

    // ---- normalize + write ctx (B,N,D) bf16; 512 thr cover 128 q x 64 d
    const int b = bh >> 4, h = bh & 15;
    const int ql = t >> 2;                          // 0..127
    const float inv = 1.0f / Lv[ql];
    const float* Orow = Osc + (ql >> 6) * 4096 + (ql & 63) * 64;
    #pragma unroll
    for (int i = 0; i < 4; ++i) {
        const int d0 = (t & 3) * 16 + i * 4;
        const float4 ov = *(const float4*)(Orow + d0);
        us4 u = {f2bf(ov.x * inv), f2bf(ov.y * inv),
                 f2bf(ov.z * inv), f2bf(ov.w * inv)};
        *(us4*)&ctx[((size_t)b * NN + q0 + ql) * DD + h * 64 + d0] = u;
    }
}

// ---------------------------------------------------------------------------
extern "C" void kernel_launch(void* const* d_in, const int* in_sizes, int n_in,
                              void* d_out, int out_size, void* d_ws, size_t ws_size,
                              hipStream_t stream)
{
    const float* q   = (const float*)d_in[0];
    const float* k   = (const float*)d_in[1];
    const float* v   = (const float*)d_in[2];
    const float* wq  = (const float*)d_in[3];
    const float* wk  = (const float*)d_in[4];
    const float* wv  = (const float*)d_in[5];
    const float* wo  = (const float*)d_in[6];
    const float* rot = (const float*)d_in[7];

    float* out_final = (float*)d_out;            // (B,N,D)
    float* out_kt    = out_final + OUTSZ;        // (B,H,HD,N)
    float* out_vh    = out_kt + OUTSZ;           // (B,H,N,HD)

    u16* wsb  = (u16*)d_ws;
    u16* qb   = wsb;
    u16* kb   = wsb + (size_t) 4 * 1024 * 1024;
    u16* vb   = wsb + (size_t) 8 * 1024 * 1024;
    u16* wqb  = wsb + (size_t)12 * 1024 * 1024;
    u16* wkb  = wsb + (size_t)13 * 1024 * 1024;
    u16* wvb  = wsb + (size_t)14 * 1024 * 1024;
    u16* wob  = wsb + (size_t)15 * 1024 * 1024;
    u16* qhb  = wsb + (size_t)16 * 1024 * 1024;  // (B,H,N,HD), pre-scaled 0.125*log2e
    u16* khb  = wsb + (size_t)20 * 1024 * 1024;  // (B,H,N,HD)
    u16* vtb  = wsb + (size_t)24 * 1024 * 1024;  // (B,H,HD,N)
    u16* ctxb = wsb + (size_t)28 * 1024 * 1024;  // (B,N,D)

    CastArgs ca;
    ca.s[0] = q;  ca.d[0] = qb;  ca.n[0] = OUTSZ;
    ca.s[1] = k;  ca.d[1] = kb;  ca.n[1] = OUTSZ;
    ca.s[2] = v;  ca.d[2] = vb;  ca.n[2] = OUTSZ;
    ca.s[3] = wq; ca.d[3] = wqb; ca.n[3] = DD * DD;
    ca.s[4] = wk; ca.d[4] = wkb; ca.n[4] = DD * DD;
    ca.s[5] = wv; ca.d[5] = wvb; ca.n[5] = DD * DD;
    ca.s[6] = wo; ca.d[6] = wob; ca.n[6] = DD * DD;
    cast_bf16<<<dim3(256, 7), 256, 0, stream>>>(ca);

    ProjArgs pa;
    pa.X[0] = qb;   pa.W[0] = wqb; pa.outf[0] = nullptr;   pa.outb[0] = qhb;
    pa.X[1] = kb;   pa.W[1] = wkb; pa.outf[1] = out_kt;    pa.outb[1] = khb;
    pa.X[2] = vb;   pa.W[2] = wvb; pa.outf[2] = out_vh;    pa.outb[2] = vtb;
    pa.X[3] = ctxb; pa.W[3] = wob; pa.outf[3] = out_final; pa.outb[3] = nullptr;
    pa.rot = rot;

    // fused Q/K/V projections: 768 blocks, 128x128 tiles, BK=64
    mfma_proj<128><<<dim3(DD / 128, (2 * NN) / 128, 3), 256, 0, stream>>>(pa, 0);

    // attention: 512 blocks (QBLK=128), head -> XCD pinned via bh on x
    mfma_attn<<<dim3(2 * HH, NN / 128), 512, 0, stream>>>(qhb, khb, vtb, ctxb);

    // final projection: 512 blocks (2/CU), 128x64 tiles, BK=64
    mfma_proj<64><<<dim3(DD / 64, (2 * NN) / 128, 1), 256, 0, stream>>>(pa, 3);
}

// Round 9
// 234.252 us; speedup vs baseline: 1.0746x; 1.0118x over previous
//
#include <hip/hip_runtime.h>
#include <math.h>

// (B,N,D,H) = (2,2048,1024,16), HD=64, ROT=32
#define NN 2048
#define DD 1024
#define HH 16
#define OUTSZ (2*NN*DD)

typedef unsigned short u16;
typedef unsigned int u32;
typedef __attribute__((ext_vector_type(8))) short short8;     // 8 bf16 (4 VGPRs)
typedef __attribute__((ext_vector_type(4))) float floatx4;
typedef __attribute__((ext_vector_type(16))) float floatx16;
typedef __attribute__((ext_vector_type(4))) u32 uint4v;
typedef __attribute__((ext_vector_type(4))) unsigned short us4;
typedef __attribute__((ext_vector_type(8))) unsigned short us8;

__device__ __forceinline__ u16 f2bf(float x) {
    union { float f; unsigned u; } v; v.f = x;
    unsigned r = v.u + 0x7FFFu + ((v.u >> 16) & 1u);   // RNE
    return (u16)(r >> 16);
}

__device__ __forceinline__ float fexp2(float x) {
#if __has_builtin(__builtin_amdgcn_exp2f)
    return __builtin_amdgcn_exp2f(x);
#else
    return __expf(x * 0.69314718056f);
#endif
}

__device__ __forceinline__ void gl_lds16(const u16* g, u16* l) {
    __builtin_amdgcn_global_load_lds(
        (const __attribute__((address_space(1))) unsigned int*)g,
        (__attribute__((address_space(3))) unsigned int*)l, 16, 0, 0);
}

// ---------------------------------------------------------------------------
// fp32 -> bf16 cast for q,k,v + 4 weights (R6-proven).
// ---------------------------------------------------------------------------
struct CastArgs { const float* s[7]; u16* d[7]; int n[7]; };

__global__ __launch_bounds__(256)
void cast_bf16(CastArgs a) {
    const int ten = blockIdx.y;
    const float4* s = (const float4*)a.s[ten];
    us8* d = (us8*)a.d[ten];
    const int n8 = a.n[ten] >> 3;
    for (int i = blockIdx.x * 256 + threadIdx.x; i < n8; i += gridDim.x * 256) {
        float4 f0 = s[2 * i];
        float4 f1 = s[2 * i + 1];
        us8 u = {f2bf(f0.x), f2bf(f0.y), f2bf(f0.z), f2bf(f0.w),
                 f2bf(f1.x), f2bf(f1.y), f2bf(f1.z), f2bf(f1.w)};
        d[i] = u;
    }
}

struct ProjArgs {
    const u16* X[4]; const u16* W[4];
    float* outf[4];  u16* outb[4];
    const float* rot;
};

// ---------------------------------------------------------------------------
// QKV projection, 256x256 tile, BK=64, 512 thr (8 waves, 2M x 4N),
// depth-2 counted-vmcnt pipeline (T3/T4), 128 KB DYNAMIC LDS.
//   prologue: STAGE(0,b0); STAGE(1,b1)           (16 loads/thread in flight)
//   iter it : s_waitcnt vmcnt(8)  <- drains ONLY tile it's 8 loads; tile
//             it+1's 8 stay in flight across the barrier (never vmcnt(0)
//             in the steady loop — the R3-structure's ~35% drain stall)
//             s_barrier; 24x ds_read_b128; 64 MFMA/wave; s_barrier
//             STAGE(it+2, buf[it&1])             (full iteration to land)
// The attribute enabling >64KB dynamic LDS is set in a GLOBAL CTOR at
// dlopen time — NOT in kernel_launch (R4's graph-capture tripwire).
// Swizzle/epilogue identical to the R3/R6-proven 128-tile kernel.
// ---------------------------------------------------------------------------
#define BM 256
#define BN 256
#define BK 64
#define NT (DD / BK)     // 16 K-tiles

__global__ __launch_bounds__(512, 2)
void mfma_proj256(ProjArgs a, int mode_base)
{
    extern __shared__ __align__(16) u16 smem[];   // 128 KB
    u16* smA = smem;                  // [2][BM*BK]
    u16* smB = smem + 2 * BM * BK;    // [2][BN*BK]

    constexpr u32 GX = DD / BN;           // 4 col tiles
    constexpr u32 GY = (2 * NN) / BM;     // 16 row tiles

    // ---- XCD-aware bijective remap (nwg = 192, %8==0)
    const u32 bid = blockIdx.x + GX * (blockIdx.y + GY * blockIdx.z);
    const u32 nwg = GX * GY * gridDim.z;
    const u32 wid = (bid & 7) * (nwg >> 3) + (bid >> 3);
    const u32 bx  = wid % GX;
    const u32 by  = (wid / GX) % GY;
    const u32 bz  = wid / (GX * GY);

    const int mode = mode_base + bz;
    const u16* __restrict__ X   = a.X[mode];
    const u16* __restrict__ Wm  = a.W[mode];
    float* __restrict__ outf    = a.outf[mode];
    u16* __restrict__ outb      = a.outb[mode];
    const float* __restrict__ rot = a.rot;

    const int t    = threadIdx.x;
    const int lane = t & 63;
    const int w    = t >> 6;
    const int wm   = (w >> 2) * 128;   // wave row base (0,128)
    const int wn   = (w & 3) * 64;     // wave col base (0,64,128,192)
    const int m0   = by * BM;
    const int j0   = bx * BN;
    const int fr   = lane & 15;
    const int fq   = lane >> 4;

    // staging: thread t covers row r0(+64p), chunk t&7; global pre-swizzled
    const int r0 = t >> 3;
    const int lc = (t & 7) ^ (r0 & 7);
    const u16* gA = X  + (size_t)(m0 + r0) * DD + lc * 8;
    const u16* gB = Wm + (size_t)(j0 + r0) * DD + lc * 8;

#define STAGE(kt, buf) do {                                                        \
        const int _k0 = (kt) * BK;                                                 \
        u16* _As = smA + (buf) * (BM * BK);                                        \
        u16* _Bs = smB + (buf) * (BN * BK);                                        \
        _Pragma("unroll")                                                          \
        for (int p = 0; p < 4; ++p)                                                \
            gl_lds16(gA + (size_t)(64 * p) * DD + _k0, _As + (p * 512 + t) * 8);   \
        _Pragma("unroll")                                                          \
        for (int p = 0; p < 4; ++p)                                                \
            gl_lds16(gB + (size_t)(64 * p) * DD + _k0, _Bs + (p * 512 + t) * 8);   \
    } while (0)

    floatx4 acc[8][4] = {};

    STAGE(0, 0);
    STAGE(1, 1);

    for (int it = 0; it < NT; ++it) {
        const int cur = it & 1;
        if (it < NT - 1) asm volatile("s_waitcnt vmcnt(8)" ::: "memory");
        else             asm volatile("s_waitcnt vmcnt(0)" ::: "memory");
        __builtin_amdgcn_s_barrier();

        const u16* As = smA + cur * (BM * BK);
        const u16* Bs = smB + cur * (BN * BK);
        #pragma unroll
        for (int kk = 0; kk < 2; ++kk) {
            const int ph = (kk * 4 + fq) ^ (fr & 7);
            short8 af[8], bf[4];
            #pragma unroll
            for (int i = 0; i < 8; ++i)
                af[i] = *(const short8*)(As + (wm + i * 16 + fr) * 64 + ph * 8);
            #pragma unroll
            for (int j = 0; j < 4; ++j)
                bf[j] = *(const short8*)(Bs + (wn + j * 16 + fr) * 64 + ph * 8);
            #pragma unroll
            for (int i = 0; i < 8; ++i)
                #pragma unroll
                for (int j = 0; j < 4; ++j)
                    acc[i][j] = __builtin_amdgcn_mfma_f32_16x16x32_bf16(af[i], bf[j], acc[i][j], 0, 0, 0);
        }

        __builtin_amdgcn_s_barrier();              // all reads of buf[cur] done
        if (it + 2 < NT) STAGE(it + 2, cur);       // refill freed buffer
    }
#undef STAGE

    const int b = m0 >> 11;
    #pragma unroll
    for (int i = 0; i < 8; ++i) {
        const int mrow  = m0 + wm + i * 16 + fq * 4;   // + r
        const int nbase = mrow & (NN - 1);
        #pragma unroll
        for (int j = 0; j < 4; ++j) {
            const int col = j0 + wn + j * 16 + fr;
            const int h = col >> 6, d = col & 63;
            const int bh = b * HH + h;
            float v[4];
            #pragma unroll
            for (int r = 0; r < 4; ++r) v[r] = acc[i][j][r];
            // rotary applies to head-dims d<32; (wn + j*16) & 63 == j*16
            if (mode <= 1 && ((wn + j * 16) & 63) < 32) {
                #pragma unroll
                for (int r = 0; r < 4; ++r) {
                    const int n = nbase + r;
                    float c = v[r];
                    float p = __shfl_xor(c, 1);     // partner element d^1
                    float f = rot[n * 32 + d];
                    float sn, cs; __sincosf(f, &sn, &cs);
                    v[r] = (d & 1) ? fmaf(c, cs, p * sn) : fmaf(c, cs, -p * sn);
                }
            }
            if (mode == 0) {
                // fold softmax scale 1/8 and log2(e) into Q
                #pragma unroll
                for (int r = 0; r < 4; ++r)
                    outb[((size_t)bh * NN + nbase + r) * 64 + d] = f2bf(v[r] * 0.1803368801111244f);
            } else if (mode == 1) {
                float4 f4 = {v[0], v[1], v[2], v[3]};
                *(float4*)&outf[((size_t)bh * 64 + d) * NN + nbase] = f4;
                #pragma unroll
                for (int r = 0; r < 4; ++r)
                    outb[((size_t)bh * NN + nbase + r) * 64 + d] = f2bf(v[r]);
            } else {  // mode == 2
                #pragma unroll
                for (int r = 0; r < 4; ++r)
                    outf[((size_t)bh * NN + nbase + r) * 64 + d] = v[r];
                us4 u = {f2bf(v[0]), f2bf(v[1]), f2bf(v[2]), f2bf(v[3])};
                *(us4*)&outb[((size_t)bh * 64 + d) * NN + nbase] = u;
            }
        }
    }
}

// enable 128 KB dynamic LDS at dlopen time — OUTSIDE graph capture (R4 lesson)
namespace {
struct SmemInitProj {
    SmemInitProj() {
        hipFuncSetAttribute((const void*)mfma_proj256,
                            hipFuncAttributeMaxDynamicSharedMemorySize, 131072);
    }
};
static SmemInitProj g_smem_init_proj;
}

// ---------------------------------------------------------------------------
// Final projection (R3/R6-proven): tile 128 x 64, BK=64, 256 thr, 512 blocks.
// ---------------------------------------------------------------------------
template<int TN>
__global__ __launch_bounds__(256)
void mfma_proj(ProjArgs a, int mode_base)
{
    constexpr int TNW = TN / 2;      // wave cols
    constexpr int NJ  = TNW / 16;    // B-fragments per wave
    constexpr u32 GX  = DD / TN;     // col tiles
    constexpr u32 GY  = (2 * NN) / 128;

    __shared__ __align__(16) u16 As[128 * 64];
    __shared__ __align__(16) u16 Bs[TN * 64];

    const u32 bid = blockIdx.x + GX * (blockIdx.y + GY * blockIdx.z);
    const u32 nwg = GX * GY * gridDim.z;
    const u32 wid = (bid & 7) * (nwg >> 3) + (bid >> 3);
    const u32 bx  = wid % GX;
    const u32 by  = (wid / GX) % GY;
    const u32 bz  = wid / (GX * GY);

    const int mode = mode_base + bz;
    const u16* __restrict__ X   = a.X[mode];
    const u16* __restrict__ Wm  = a.W[mode];
    float* __restrict__ outf    = a.outf[mode];
    const int t    = threadIdx.x;
    const int lane = t & 63;
    const int w    = t >> 6;
    const int wr   = (w >> 1) * 64;
    const int wc   = (w & 1) * TNW;
    const int m0   = by * 128;
    const int j0   = bx * TN;

    const int lc = (t & 7) ^ ((t >> 3) & 7);
    const u16* gA = X  + (size_t)(m0 + (t >> 3)) * DD + lc * 8;
    const u16* gB = Wm + (size_t)(j0 + (t >> 3)) * DD + lc * 8;

    const int fr = lane & 15;
    const int fq = lane >> 4;

    floatx4 acc[4][NJ] = {};

    for (int k0 = 0; k0 < DD; k0 += 64) {
        __syncthreads();
        #pragma unroll
        for (int p = 0; p < 4; ++p)
            gl_lds16(gA + (size_t)(32 * p) * DD + k0, As + (p * 256 + t) * 8);
        #pragma unroll
        for (int p = 0; p < TN / 32; ++p)
            gl_lds16(gB + (size_t)(32 * p) * DD + k0, Bs + (p * 256 + t) * 8);
        __syncthreads();
        #pragma unroll
        for (int kk = 0; kk < 2; ++kk) {
            const int ph = (kk * 4 + fq) ^ (fr & 7);
            short8 af[4], bf[NJ];
            #pragma unroll
            for (int i = 0; i < 4; ++i)
                af[i] = *(const short8*)(As + (wr + i * 16 + fr) * 64 + ph * 8);
            #pragma unroll
            for (int j = 0; j < NJ; ++j)
                bf[j] = *(const short8*)(Bs + (wc + j * 16 + fr) * 64 + ph * 8);
            #pragma unroll
            for (int i = 0; i < 4; ++i)
                #pragma unroll
                for (int j = 0; j < NJ; ++j)
                    acc[i][j] = __builtin_amdgcn_mfma_f32_16x16x32_bf16(af[i], bf[j], acc[i][j], 0, 0, 0);
        }
    }

    #pragma unroll
    for (int i = 0; i < 4; ++i) {
        const int mrow = m0 + wr + i * 16 + fq * 4;
        #pragma unroll
        for (int j = 0; j < NJ; ++j) {
            const int col = j0 + wc + j * 16 + fr;
            #pragma unroll
            for (int r = 0; r < 4; ++r)
                outf[(size_t)(mrow + r) * DD + col] = acc[i][j][r];
        }
    }
}

// ---------------------------------------------------------------------------
// bf16 MFMA flash attention v4 (R8): QBLK=128, 512 thr, 8 waves =
// 2 q-halves x 4 key-slices; 32x32 swapped QK^T, in-register P (T12).
// ---------------------------------------------------------------------------
__global__ __launch_bounds__(512, 2)
void mfma_attn(const u16* __restrict__ qh, const u16* __restrict__ kh,
               const u16* __restrict__ vt, u16* __restrict__ ctx)
{
    __shared__ __align__(16) u16 Ks[2][128 * 64];   // [buf][key][hd], 16 KB each
    __shared__ __align__(16) u16 Vs[2][64 * 128];   // [buf][hd][key], 16 KB each

    const int t    = threadIdx.x;
    const int lane = t & 63;
    const int w    = t >> 6;                        // 0..7
    const int m    = lane & 31;
    const int hi   = lane >> 5;
    const int g    = w >> 2;                        // q-half
    const int s    = w & 3;                         // key-slice
    const int bh   = blockIdx.x;                    // head -> XCD pin (bh%8)
    const int q0   = blockIdx.y * 128;

    short8 qf[2][4];
    #pragma unroll
    for (int c = 0; c < 2; ++c)
        #pragma unroll
        for (int kk = 0; kk < 4; ++kk)
            qf[c][kk] = *(const short8*)(qh +
                ((size_t)bh * NN + q0 + g * 64 + c * 32 + m) * 64 + kk * 16 + hi * 8);

    const int kr = t >> 3, kc = t & 7;
    const u16* kg = kh + ((size_t)bh * NN + kr) * 64 + (kc ^ (kr & 7)) * 8;
    const int dt = t >> 4, vc = t & 15;
    const u16* vg = vt + ((size_t)bh * 64 + dt) * NN + (vc ^ (dt & 15)) * 8;

    int kfo[4], vfo[2][2];
    #pragma unroll
    for (int kk = 0; kk < 4; ++kk)
        kfo[kk] = (s * 32 + m) * 64 + (((kk * 2 + hi) ^ (m & 7)) * 8);
    #pragma unroll
    for (int n = 0; n < 2; ++n)
        #pragma unroll
        for (int ks = 0; ks < 2; ++ks) {
            const int d = n * 32 + m;
            vfo[n][ks] = d * 128 + (((s * 4 + ks * 2 + hi) ^ (d & 15)) * 8);
        }

    floatx16 o[2][2] = {};
    float lrun[2] = {0.f, 0.f};

    #pragma unroll
    for (int p = 0; p < 2; ++p) {
        gl_lds16(kg + (size_t)(p * 64) * 64, &Ks[0][(p * 512 + t) * 8]);
        gl_lds16(vg + (size_t)(p * 32) * NN, &Vs[0][(p * 512 + t) * 8]);
    }

    for (int it = 0; it < NN / 128; ++it) {
        const int cur = it & 1;
        __syncthreads();
        if (it + 1 < NN / 128) {
            const int j1 = (it + 1) * 128;
            #pragma unroll
            for (int p = 0; p < 2; ++p) {
                gl_lds16(kg + (size_t)(j1 + p * 64) * 64, &Ks[cur ^ 1][(p * 512 + t) * 8]);
                gl_lds16(vg + (size_t)(p * 32) * NN + j1, &Vs[cur ^ 1][(p * 512 + t) * 8]);
            }
        }
        const u16* kb = Ks[cur];
        const u16* vb = Vs[cur];

        short8 kf[4];
        #pragma unroll
        for (int kk = 0; kk < 4; ++kk)
            kf[kk] = *(const short8*)(kb + kfo[kk]);
        short8 vf[2][2];
        #pragma unroll
        for (int n = 0; n < 2; ++n)
            #pragma unroll
            for (int ks = 0; ks < 2; ++ks)
                vf[n][ks] = *(const short8*)(vb + vfo[n][ks]);

        floatx16 sT[2] = {};
        __builtin_amdgcn_s_setprio(1);
        #pragma unroll
        for (int kk = 0; kk < 4; ++kk) {
            sT[0] = __builtin_amdgcn_mfma_f32_32x32x16_bf16(kf[kk], qf[0][kk], sT[0], 0, 0, 0);
            sT[1] = __builtin_amdgcn_mfma_f32_32x32x16_bf16(kf[kk], qf[1][kk], sT[1], 0, 0, 0);
        }
        __builtin_amdgcn_s_setprio(0);

        #pragma unroll
        for (int c = 0; c < 2; ++c) {
            float p[16];
            #pragma unroll
            for (int r = 0; r < 16; ++r) p[r] = fexp2(sT[c][r]);
            lrun[c] += ((((p[0] + p[1]) + (p[2] + p[3])) + ((p[4] + p[5]) + (p[6] + p[7])))
                     + (((p[8] + p[9]) + (p[10] + p[11])) + ((p[12] + p[13]) + (p[14] + p[15]))));
            u32 W[8];
            #pragma unroll
            for (int ss = 0; ss < 8; ++ss)
                asm("v_cvt_pk_bf16_f32 %0, %1, %2" : "=v"(W[ss]) : "v"(p[2 * ss]), "v"(p[2 * ss + 1]));
            asm("v_permlane32_swap_b32 %0, %1" : "+v"(W[0]), "+v"(W[2]));
            asm("v_permlane32_swap_b32 %0, %1" : "+v"(W[1]), "+v"(W[3]));
            asm("v_permlane32_swap_b32 %0, %1" : "+v"(W[4]), "+v"(W[6]));
            asm("v_permlane32_swap_b32 %0, %1" : "+v"(W[5]), "+v"(W[7]));
            uint4v w0 = {W[0], W[1], W[2], W[3]};
            uint4v w1 = {W[4], W[5], W[6], W[7]};
            const short8 pa0 = __builtin_bit_cast(short8, w0);
            const short8 pa1 = __builtin_bit_cast(short8, w1);
            __builtin_amdgcn_s_setprio(1);
            #pragma unroll
            for (int n = 0; n < 2; ++n) {
                o[c][n] = __builtin_amdgcn_mfma_f32_32x32x16_bf16(pa0, vf[n][0], o[c][n], 0, 0, 0);
                o[c][n] = __builtin_amdgcn_mfma_f32_32x32x16_bf16(pa1, vf[n][1], o[c][n], 0, 0, 0);
            }
            __builtin_amdgcn_s_setprio(0);
        }
    }

    #pragma unroll
    for (int c = 0; c < 2; ++c)
        lrun[c] += __shfl_xor(lrun[c], 32);

    float* Osc = (float*)&Ks[0][0];
    float* Lv  = (float*)&Vs[0][0];

    __syncthreads();
    #pragma unroll
    for (int rnd = 0; rnd < 4; ++rnd) {
        if (s == rnd) {
            float* O = Osc + g * 4096;
            #pragma unroll
            for (int c = 0; c < 2; ++c) {
                #pragma unroll
                for (int n = 0; n < 2; ++n)
                    #pragma unroll
                    for (int r = 0; r < 16; ++r) {
                        const int q = c * 32 + (r & 3) + 8 * (r >> 2) + 4 * hi;
                        if (rnd == 0) O[q * 64 + n * 32 + m] = o[c][n][r];
                        else          O[q * 64 + n * 32 + m] += o[c][n][r];
                    }
                if (hi == 0) {
                    const int ql = g * 64 + c * 32 + m;
                    if (rnd == 0) Lv[ql] = lrun[c];
                    else          Lv[ql] += lrun[c];
                }
            }
        }
        __syncthreads();
    }

    const int b = bh >> 4, h = bh & 15;
    const int ql = t >> 2;                          // 0..127
    const float inv = 1.0f / Lv[ql];
    const float* Orow = Osc + (ql >> 6) * 4096 + (ql & 63) * 64;
    #pragma unroll
    for (int i = 0; i < 4; ++i) {
        const int d0 = (t & 3) * 16 + i * 4;
        const float4 ov = *(const float4*)(Orow + d0);
        us4 u = {f2bf(ov.x * inv), f2bf(ov.y * inv),
                 f2bf(ov.z * inv), f2bf(ov.w * inv)};
        *(us4*)&ctx[((size_t)b * NN + q0 + ql) * DD + h * 64 + d0] = u;
    }
}

// ---------------------------------------------------------------------------
extern "C" void kernel_launch(void* const* d_in, const int* in_sizes, int n_in,
                              void* d_out, int out_size, void* d_ws, size_t ws_size,
                              hipStream_t stream)
{
    const float* q   = (const float*)d_in[0];
    const float* k   = (const float*)d_in[1];
    const float* v   = (const float*)d_in[2];
    const float* wq  = (const float*)d_in[3];
    const float* wk  = (const float*)d_in[4];
    const float* wv  = (const float*)d_in[5];
    const float* wo  = (const float*)d_in[6];
    const float* rot = (const float*)d_in[7];

    float* out_final = (float*)d_out;            // (B,N,D)
    float* out_kt    = out_final + OUTSZ;        // (B,H,HD,N)
    float* out_vh    = out_kt + OUTSZ;           // (B,H,N,HD)

    u16* wsb  = (u16*)d_ws;
    u16* qb   = wsb;
    u16* kb   = wsb + (size_t) 4 * 1024 * 1024;
    u16* vb   = wsb + (size_t) 8 * 1024 * 1024;
    u16* wqb  = wsb + (size_t)12 * 1024 * 1024;
    u16* wkb  = wsb + (size_t)13 * 1024 * 1024;
    u16* wvb  = wsb + (size_t)14 * 1024 * 1024;
    u16* wob  = wsb + (size_t)15 * 1024 * 1024;
    u16* qhb  = wsb + (size_t)16 * 1024 * 1024;  // (B,H,N,HD), pre-scaled 0.125*log2e
    u16* khb  = wsb + (size_t)20 * 1024 * 1024;  // (B,H,N,HD)
    u16* vtb  = wsb + (size_t)24 * 1024 * 1024;  // (B,H,HD,N)
    u16* ctxb = wsb + (size_t)28 * 1024 * 1024;  // (B,N,D)

    CastArgs ca;
    ca.s[0] = q;  ca.d[0] = qb;  ca.n[0] = OUTSZ;
    ca.s[1] = k;  ca.d[1] = kb;  ca.n[1] = OUTSZ;
    ca.s[2] = v;  ca.d[2] = vb;  ca.n[2] = OUTSZ;
    ca.s[3] = wq; ca.d[3] = wqb; ca.n[3] = DD * DD;
    ca.s[4] = wk; ca.d[4] = wkb; ca.n[4] = DD * DD;
    ca.s[5] = wv; ca.d[5] = wvb; ca.n[5] = DD * DD;
    ca.s[6] = wo; ca.d[6] = wob; ca.n[6] = DD * DD;
    cast_bf16<<<dim3(256, 7), 256, 0, stream>>>(ca);

    ProjArgs pa;
    pa.X[0] = qb;   pa.W[0] = wqb; pa.outf[0] = nullptr;   pa.outb[0] = qhb;
    pa.X[1] = kb;   pa.W[1] = wkb; pa.outf[1] = out_kt;    pa.outb[1] = khb;
    pa.X[2] = vb;   pa.W[2] = wvb; pa.outf[2] = out_vh;    pa.outb[2] = vtb;
    pa.X[3] = ctxb; pa.W[3] = wob; pa.outf[3] = out_final; pa.outb[3] = nullptr;
    pa.rot = rot;

    // fused Q/K/V projections: 192 blocks, 256x256 tiles, counted-vmcnt
    mfma_proj256<<<dim3(DD / BN, (2 * NN) / BM, 3), 512, 131072, stream>>>(pa, 0);

    // attention: 512 blocks (QBLK=128), head -> XCD pinned via bh on x
    mfma_attn<<<dim3(2 * HH, NN / 128), 512, 0, stream>>>(qhb, khb, vtb, ctxb);

    // final projection: 512 blocks (2/CU), 128x64 tiles, BK=64
    mfma_proj<64><<<dim3(DD / 64, (2 * NN) / 128, 1), 256, 0, stream>>>(pa, 3);
}